// Round 8
// baseline (817.069 us; speedup 1.0000x reference)
//
#include <hip/hip_runtime.h>
#include <hip/hip_bf16.h>
#include <stdint.h>

#define B_TOTAL 262144
#define TB 64
#define RECORD 2560         // 10 stream-slots * 256B per row
#define LDS_BYTES 163840    // 64 rows * 2560 = 160 KiB exactly
#define HEAD_W 204800       // bf16 weight elements per head in d_ws

typedef short v8s __attribute__((ext_vector_type(8)));
typedef float v4f __attribute__((ext_vector_type(4)));

union Frag { uint4 q; uint32_t d[4]; v8s v; };

__device__ __forceinline__ uint32_t pack2(float a, float b) {
    union { __hip_bfloat162 h; uint32_t u; } p;
    p.h = __float22bfloat162_rn(make_float2(a, b));
    return p.u;
}

// LDS layout: addr(row, slot, gg) = row*2560 + slot*256 + ((gg ^ (row&15))<<4)
// Zero-VALU DS addressing (verified R2). Slot map (head-interleaved, R7):
//   S0   : xu (both L1 phases), then h1-main in-place after bar2
//   S1-5 : h0 streams, rewritten in-place L1->L2
//   S6-9 : h1 teachers
//   pgrid-h0: bytes [256,1280) row 0 ; pgrid-h1: bytes [1536,2560) row 0
//
// NEW this round: one-region-lookahead weight prefetch (R0's trick inside
// R7's interleave). Region i issues region-(i+1)'s weight loads, chunked in
// two 40-reg halves woven between MFMA half-phases so peak liveness stays
// ~wCur(80,dying) + wNext(<=80,arriving) + acc(80) < 256. The barrier's
// vmcnt(0) drain is the completion sync. Biases left OUT of the preload
// (20 regs saved) and loaded transiently in the epilogue (L1-hot).

struct KParams {
    const float* x; const float* u; const float* mix; const float* P;
    const float* mb[6];
    const float* tb[6];
    const float* Wout[2];
    const float* bout[2];
    const unsigned short* wbf;
    float* out;
};

struct PrepParams { const float* src[12]; unsigned short* dst; };

__global__ __launch_bounds__(256) void prep_kernel(PrepParams pp) {
    const int ends[12] = {16384,81920,98304,163840,172032,204800,
                          221184,286720,303104,368640,376832,409600};
    int gi = (blockIdx.x * 256 + threadIdx.x) * 4;
    if (gi >= 409600) return;
    int s = 0;
    #pragma unroll
    for (int i = 0; i < 12; ++i) { if (gi >= ends[i]) s = i + 1; }
    int base = (s == 0) ? 0 : ends[s - 1];
    const float4 f = *(const float4*)(pp.src[s] + (gi - base));
    *(uint2*)(pp.dst + gi) = make_uint2(pack2(f.x, f.y), pack2(f.z, f.w));
}

__device__ __forceinline__ void stage_xu(char* lds, const float* x, const float* u,
                                         int rowBase, int tid)
{
    for (int G = tid; G < 1024; G += 512) {
        const int row = G >> 4;
        const int gg  = G & 15;
        const int grow = rowBase + row;
        float4 fa, fb;
        if (gg < 12) {
            const float* s2 = x + grow * 96 + gg * 8;
            fa = *(const float4*)s2; fb = *(const float4*)(s2 + 4);
        } else {
            const float* s2 = u + grow * 32 + (gg - 12) * 8;
            fa = *(const float4*)s2; fb = *(const float4*)(s2 + 4);
        }
        *(uint4*)(lds + row * RECORD + ((gg ^ (row & 15)) << 4)) =
            make_uint4(pack2(fa.x, fa.y), pack2(fa.z, fa.w),
                       pack2(fb.x, fb.y), pack2(fb.z, fb.w));
    }
}

// Weight fragments only (80 regs). Biases load in the epilogue.
struct WPre { Frag w[20]; };

// Fill k-step range [KB,KE) for all 5 streams (KE-KB==2 -> 40-reg chunk).
template<int N, int KB, int KE>
__device__ __forceinline__ void preload_ks(WPre& r, const unsigned short* W,
        int colBase, int lane)
{
    const int l15  = lane & 15;
    const int quad = lane >> 4;
    const unsigned short* wRow = W + (colBase + l15) * 128 + quad * 8;
    #pragma unroll
    for (int s = 0; s < 5; ++s)
        #pragma unroll
        for (int ks = KB; ks < KE; ++ks)
            r.w[s * 4 + ks].q = *(const uint4*)(wRow + s * (N * 128) + ks * 32);
}

template<int NBT>
__device__ __forceinline__ void zero_acc(v4f (&acc)[5][NBT]) {
    #pragma unroll
    for (int s = 0; s < 5; ++s)
        #pragma unroll
        for (int bt = 0; bt < NBT; ++bt)
            acc[s][bt] = (v4f){0.f, 0.f, 0.f, 0.f};
}

// MFMA k-step range [KB,KE): input streams -> acc (caller zero-inits).
// Stream s reads slot (s==0 ? SM : ST+s-1); SHARED_IN: all 5 read SM (=xu).
// Acc per lane: batch row bt*16+(lane&15), out cols obase+(lane>>4)*4+r.
template<bool SHARED_IN, int SM, int ST, int NBT, int KB, int KE>
__device__ __forceinline__ void mfma_part(const char* lds, uint32_t btOff,
        const WPre& wp, v4f (&acc)[5][NBT], int lane)
{
    const int l15  = lane & 15;
    const int quad = lane >> 4;
    const uint32_t rb = (uint32_t)l15 * RECORD + ((uint32_t)l15 << 4) + btOff;

    #pragma unroll
    for (int ks = KB; ks < KE; ++ks) {
        const uint32_t rA = rb ^ (uint32_t)(((ks << 2) | quad) << 4);
        Frag xS[NBT];
        if constexpr (SHARED_IN) {
            #pragma unroll
            for (int bt = 0; bt < NBT; ++bt)
                xS[bt].q = *(const uint4*)(lds + rA
                            + (uint32_t)(bt * 40960 + SM * 256));
        }
        #pragma unroll
        for (int s = 0; s < 5; ++s) {
            Frag xF[NBT];
            if constexpr (!SHARED_IN) {
                const int slot = (s == 0) ? SM : (ST + s - 1);
                #pragma unroll
                for (int bt = 0; bt < NBT; ++bt)
                    xF[bt].q = *(const uint4*)(lds + rA
                                + (uint32_t)(bt * 40960 + slot * 256));
            }
            #pragma unroll
            for (int bt = 0; bt < NBT; ++bt)
                acc[s][bt] = __builtin_amdgcn_mfma_f32_16x16x32_bf16(
                    wp.w[s * 4 + ks].v, (SHARED_IN ? xS[bt].v : xF[bt].v),
                    acc[s][bt], 0, 0, 0);
        }
    }
}

// Epilogue: load biases (transient, L1-hot), mix + relu, write 5 streams.
// Main -> slot WM, teacher s -> WT+s. In-place safe after reads-done barrier.
template<int WM, int WT, int N>
__device__ __forceinline__ void write_streams(char* lds, v4f (&acc)[5][4],
        float c0, const float* cP, int lane, int colBase,
        const float* mbias, const float* tbias)
{
    const int l15  = lane & 15;
    const int quad = lane >> 4;
    const int obase = colBase + (quad << 2);
    const float4 mB = *(const float4*)(mbias + obase);
    float4 tB[4];
    #pragma unroll
    for (int s = 0; s < 4; ++s)
        tB[s] = *(const float4*)(tbias + s * N + obase);

    const uint32_t rb = (uint32_t)l15 * RECORD + ((uint32_t)l15 << 4);
    const int ocg = (colBase >> 3) + (quad >> 1);
    const uint32_t w0 = (rb ^ ((uint32_t)ocg << 4)) + (uint32_t)((quad & 1) << 3);
    #pragma unroll
    for (int bt = 0; bt < 4; ++bt) {
        char* ab = lds + (w0 + (uint32_t)(bt * 40960));
        float vr[4];
        vr[0] = c0 * (acc[0][bt][0] + mB.x);
        vr[1] = c0 * (acc[0][bt][1] + mB.y);
        vr[2] = c0 * (acc[0][bt][2] + mB.z);
        vr[3] = c0 * (acc[0][bt][3] + mB.w);
        uint2 tw[4];
        #pragma unroll
        for (int s = 0; s < 4; ++s) {
            const float t0 = acc[s + 1][bt][0] + tB[s].x;
            const float t1 = acc[s + 1][bt][1] + tB[s].y;
            const float t2 = acc[s + 1][bt][2] + tB[s].z;
            const float t3 = acc[s + 1][bt][3] + tB[s].w;
            vr[0] = fmaf(cP[s], t0, vr[0]);
            vr[1] = fmaf(cP[s], t1, vr[1]);
            vr[2] = fmaf(cP[s], t2, vr[2]);
            vr[3] = fmaf(cP[s], t3, vr[3]);
            tw[s] = make_uint2(pack2(fmaxf(t0, 0.f), fmaxf(t1, 0.f)),
                               pack2(fmaxf(t2, 0.f), fmaxf(t3, 0.f)));
        }
        *(uint2*)(ab + WM * 256) =
            make_uint2(pack2(fmaxf(vr[0], 0.f), fmaxf(vr[1], 0.f)),
                       pack2(fmaxf(vr[2], 0.f), fmaxf(vr[3], 0.f)));
        #pragma unroll
        for (int s = 0; s < 4; ++s)
            *(uint2*)(ab + (WT + s) * 256) = tw[s];
    }
}

// Final L3+L4 combine: biases + mix + relu + Wout dot + reduce -> pgrid.
__device__ __forceinline__ void psum_write(const v4f (&accF)[5][2], float c0,
        const float* cP, const float* Wout, const float* mbias,
        const float* tbias, float* pgrid, int lane, int cb64, int btB64)
{
    const int obase = cb64 + ((lane >> 4) << 2);
    const float4 mB = *(const float4*)(mbias + obase);
    float4 tB[4];
    #pragma unroll
    for (int s = 0; s < 4; ++s)
        tB[s] = *(const float4*)(tbias + s * 64 + obase);
    const float4 wo = *(const float4*)(Wout + obase);
    #pragma unroll
    for (int j = 0; j < 2; ++j) {
        float vr[4];
        vr[0] = c0 * (accF[0][j][0] + mB.x);
        vr[1] = c0 * (accF[0][j][1] + mB.y);
        vr[2] = c0 * (accF[0][j][2] + mB.z);
        vr[3] = c0 * (accF[0][j][3] + mB.w);
        #pragma unroll
        for (int s = 0; s < 4; ++s) {
            vr[0] = fmaf(cP[s], accF[s + 1][j][0] + tB[s].x, vr[0]);
            vr[1] = fmaf(cP[s], accF[s + 1][j][1] + tB[s].y, vr[1]);
            vr[2] = fmaf(cP[s], accF[s + 1][j][2] + tB[s].z, vr[2]);
            vr[3] = fmaf(cP[s], accF[s + 1][j][3] + tB[s].w, vr[3]);
        }
        float pp = fmaxf(vr[0], 0.f) * wo.x + fmaxf(vr[1], 0.f) * wo.y
                 + fmaxf(vr[2], 0.f) * wo.z + fmaxf(vr[3], 0.f) * wo.w;
        pp += __shfl_xor(pp, 16);
        pp += __shfl_xor(pp, 32);
        if (lane < 16)
            pgrid[(cb64 >> 4) * 64 + (btB64 + j) * 16 + lane] = pp;
    }
}

extern "C" __global__ __launch_bounds__(512, 2)
void critic_kernel(KParams p)
{
    extern __shared__ char lds[];
    const int tid  = threadIdx.x;
    const int lane = tid & 63;
    const int wave = tid >> 6;            // 0..7
    const int rowBase = blockIdx.x * TB;

    const int cb128 = wave << 4;                        // 16-col group, N=128
    const int cb64  = (wave >> 1) << 4;                 // 16-col group, final
    const int btB64 = (wave & 1) << 1;                  // row-half, final
    const uint32_t btOff64 = (uint32_t)btB64 * 40960u;

    const float m  = p.mix[0];
    const float c0 = 1.f - m;
    float cP[4];
    #pragma unroll
    for (int k = 0; k < 4; ++k) cP[k] = m * p.P[k];

    const unsigned short* wb0 = p.wbf;
    const unsigned short* wb1 = p.wbf + HEAD_W;

    WPre wA, wB, wC, wD, wE, wF;

    stage_xu(lds, p.x, p.u, rowBase, tid);
    preload_ks<128, 0, 4>(wA, wb0, cb128, lane);
    __syncthreads();                                    // bar1: xu + wA ready

    // region 1: L1h0 (S0) + epi -> S1-5 ; L1h1 (S0). wB arrives in chunks.
    v4f accB[5][4];
    {
        preload_ks<128, 0, 2>(wB, wb1, cb128, lane);
        v4f accA[5][4];
        zero_acc(accA);
        mfma_part<true, 0, 0, 4, 0, 2>(lds, 0, wA, accA, lane);
        preload_ks<128, 2, 4>(wB, wb1, cb128, lane);
        mfma_part<true, 0, 0, 4, 2, 4>(lds, 0, wA, accA, lane);
        write_streams<1, 2, 128>(lds, accA, c0, cP, lane, cb128,
                                 p.mb[0], p.tb[0]);
        zero_acc(accB);
        mfma_part<true, 0, 0, 4, 0, 4>(lds, 0, wB, accB, lane);
    }
    __syncthreads();     // bar2: S0 reads done; S1-5 visible; wB consumed

    // region 2: L1h1 epi -> S0,S6-9 ; L2h0 (S1-5). wC own-region (epi-covered),
    // wD one-region lookahead.
    v4f accC[5][4];
    {
        preload_ks<128, 0, 4>(wC, wb0 + 81920, cb128, lane);
        preload_ks<128, 0, 2>(wD, wb1 + 81920, cb128, lane);
        write_streams<0, 6, 128>(lds, accB, c0, cP, lane, cb128,
                                 p.mb[3], p.tb[3]);
        zero_acc(accC);
        mfma_part<false, 1, 2, 4, 0, 2>(lds, 0, wC, accC, lane);
        preload_ks<128, 2, 4>(wD, wb1 + 81920, cb128, lane);
        mfma_part<false, 1, 2, 4, 2, 4>(lds, 0, wC, accC, lane);
    }
    __syncthreads();     // bar3: S1-5 reads done; S0,S6-9 visible; wD drained

    // region 3: L2h0 epi in-place S1-5 ; L2h1 (S0,S6-9). wE lookahead.
    v4f accD[5][4];
    {
        preload_ks<64, 0, 2>(wE, wb0 + 163840, cb64, lane);
        write_streams<1, 2, 128>(lds, accC, c0, cP, lane, cb128,
                                 p.mb[1], p.tb[1]);
        zero_acc(accD);
        mfma_part<false, 0, 6, 4, 0, 2>(lds, 0, wD, accD, lane);
        preload_ks<64, 2, 4>(wE, wb0 + 163840, cb64, lane);
        mfma_part<false, 0, 6, 4, 2, 4>(lds, 0, wD, accD, lane);
    }
    __syncthreads();     // bar4: S0,S6-9 reads done; S1-5 visible; wE drained

    // region 4: L2h1 epi in-place S0,S6-9 ; L3h0 (S1-5). wF lookahead.
    v4f accE[5][2];
    {
        preload_ks<64, 0, 2>(wF, wb1 + 163840, cb64, lane);
        write_streams<0, 6, 128>(lds, accD, c0, cP, lane, cb128,
                                 p.mb[4], p.tb[4]);
        zero_acc(accE);
        mfma_part<false, 1, 2, 2, 0, 2>(lds, btOff64, wE, accE, lane);
        preload_ks<64, 2, 4>(wF, wb1 + 163840, cb64, lane);
        mfma_part<false, 1, 2, 2, 2, 4>(lds, btOff64, wE, accE, lane);
    }
    __syncthreads();     // bar5: S1-5 reads done; S0,S6-9 visible; wF drained

    // region 5: h0 psum -> pgrid (row0 S1-4) ; L3h1 (S0,S6-9).
    v4f accF[5][2];
    {
        zero_acc(accF);
        psum_write(accE, c0, cP, p.Wout[0], p.mb[2], p.tb[2],
                   (float*)(lds + 256), lane, cb64, btB64);
        mfma_part<false, 0, 6, 2, 0, 4>(lds, btOff64, wF, accF, lane);
    }
    __syncthreads();     // bar6: S0,S6-9 reads done; pgrid-h0 visible

    // out-h0 ; h1 psum -> pgrid (row0 S6-9, disjoint from out-h0 reads)
    if (tid < 64) {
        const float* pg = (const float*)(lds + 256);
        p.out[rowBase + tid] =
            p.bout[0][0] + pg[tid] + pg[64 + tid] + pg[128 + tid] + pg[192 + tid];
    }
    psum_write(accF, c0, cP, p.Wout[1], p.mb[5], p.tb[5],
               (float*)(lds + 1536), lane, cb64, btB64);
    __syncthreads();     // bar7: pgrid-h1 visible

    if (tid < 64) {
        const float* pg = (const float*)(lds + 1536);
        p.out[B_TOTAL + rowBase + tid] =
            p.bout[1][0] + pg[tid] + pg[64 + tid] + pg[128 + tid] + pg[192 + tid];
    }
}

extern "C" void kernel_launch(void* const* d_in, const int* in_sizes, int n_in,
                              void* d_out, int out_size, void* d_ws, size_t ws_size,
                              hipStream_t stream)
{
    (void)in_sizes; (void)n_in; (void)out_size; (void)ws_size;

    PrepParams pp;
    const int sidx[12] = {4, 20, 6, 22, 8, 24, 12, 26, 14, 28, 16, 30};
    for (int i = 0; i < 12; ++i) pp.src[i] = (const float*)d_in[sidx[i]];
    pp.dst = (unsigned short*)d_ws;

    KParams kp;
    kp.x = (const float*)d_in[0];  kp.u = (const float*)d_in[1];
    kp.mix = (const float*)d_in[2]; kp.P = (const float*)d_in[3];
    const int mbi[6] = {5, 7, 9, 13, 15, 17};
    const int tbi[6] = {21, 23, 25, 27, 29, 31};
    for (int i = 0; i < 6; ++i) {
        kp.mb[i] = (const float*)d_in[mbi[i]];
        kp.tb[i] = (const float*)d_in[tbi[i]];
    }
    kp.Wout[0] = (const float*)d_in[10]; kp.Wout[1] = (const float*)d_in[18];
    kp.bout[0] = (const float*)d_in[11]; kp.bout[1] = (const float*)d_in[19];
    kp.wbf = (const unsigned short*)d_ws;
    kp.out = (float*)d_out;

    (void)hipFuncSetAttribute((const void*)critic_kernel,
                              hipFuncAttributeMaxDynamicSharedMemorySize, LDS_BYTES);

    hipLaunchKernelGGL(prep_kernel, dim3(400), dim3(256), 0, stream, pp);
    hipLaunchKernelGGL(critic_kernel, dim3(B_TOTAL / TB), dim3(512), LDS_BYTES, stream, kp);
}